// Round 4
// baseline (2139.541 us; speedup 1.0000x reference)
//
#include <hip/hip_runtime.h>
#include <hip/hip_bf16.h>

#define S_LEN 256
#define NB 32
#define UDIM 512
#define WGS 32    // workgroups per chain
#define RING 16   // fast-ring slots (sentinel-reset margin = 14 iterations)

typedef __attribute__((ext_vector_type(8))) short bf16x8;
typedef __attribute__((ext_vector_type(4))) float f32x4;
typedef __attribute__((ext_vector_type(4))) unsigned u32x4;

struct WPtrs { const float* p[8]; };
struct BPtrs { const float* p[4]; };

__device__ __forceinline__ unsigned short f2bf(float f) {
  union { float f; unsigned u; } v; v.f = f;
  unsigned r = v.u + 0x7fffu + ((v.u >> 16) & 1u);
  return (unsigned short)(r >> 16);
}
union QU { u32x4 u; bf16x8 b; };
__device__ __forceinline__ bf16x8 q2b(u32x4 v) { QU x; x.u = v; return x.b; }

// device-scope (cross-XCD) store: write-through to coherent point
__device__ __forceinline__ void st_u32c(unsigned* p, unsigned v) {
  asm volatile("global_store_dword %0, %1, off sc0 sc1" :: "v"(p), "v"(v) : "memory");
}

#define GL16(F) \
  "global_load_dwordx4 %0, %16, off " F "\n\t" \
  "global_load_dwordx4 %1, %16, off offset:64 " F "\n\t" \
  "global_load_dwordx4 %2, %16, off offset:128 " F "\n\t" \
  "global_load_dwordx4 %3, %16, off offset:192 " F "\n\t" \
  "global_load_dwordx4 %4, %16, off offset:256 " F "\n\t" \
  "global_load_dwordx4 %5, %16, off offset:320 " F "\n\t" \
  "global_load_dwordx4 %6, %16, off offset:384 " F "\n\t" \
  "global_load_dwordx4 %7, %16, off offset:448 " F "\n\t" \
  "global_load_dwordx4 %8, %17, off " F "\n\t" \
  "global_load_dwordx4 %9, %17, off offset:64 " F "\n\t" \
  "global_load_dwordx4 %10, %17, off offset:128 " F "\n\t" \
  "global_load_dwordx4 %11, %17, off offset:192 " F "\n\t" \
  "global_load_dwordx4 %12, %17, off offset:256 " F "\n\t" \
  "global_load_dwordx4 %13, %17, off offset:320 " F "\n\t" \
  "global_load_dwordx4 %14, %17, off offset:384 " F "\n\t" \
  "global_load_dwordx4 %15, %17, off offset:448 " F "\n\t"

#define QOUT(q) "=&v"(q[0]),"=&v"(q[1]),"=&v"(q[2]),"=&v"(q[3]),"=&v"(q[4]),"=&v"(q[5]), \
                "=&v"(q[6]),"=&v"(q[7]),"=&v"(q[8]),"=&v"(q[9]),"=&v"(q[10]),"=&v"(q[11]), \
                "=&v"(q[12]),"=&v"(q[13]),"=&v"(q[14]),"=&v"(q[15])

// blocking coherent 16-load (waitcnt inside)
__device__ __forceinline__ void ld16_coh(const short* p0, const short* p1, u32x4* q) {
  asm volatile(GL16("sc0 sc1") "s_waitcnt vmcnt(0)"
               : QOUT(q) : "v"(p0), "v"(p1) : "memory");
}
// blocking L2-scope 16-load (L1 bypass, hits own-XCD L2)
__device__ __forceinline__ void ld16_fast(const short* p0, const short* p1, u32x4* q) {
  asm volatile(GL16("sc0") "s_waitcnt vmcnt(0)"
               : QOUT(q) : "v"(p0), "v"(p1) : "memory");
}
// non-blocking issue (prefetch); consume after waitq()
__device__ __forceinline__ void ld16_issue(const short* p0, const short* p1, u32x4* q) {
  asm volatile(GL16("sc0 sc1")
               : QOUT(q) : "v"(p0), "v"(p1) : "memory");
}
// drain + tie q through the asm so later reads can't be hoisted above (rule 18)
__device__ __forceinline__ void waitq(u32x4* q) {
  asm volatile("s_waitcnt vmcnt(0)"
               : "+v"(q[0]),"+v"(q[1]),"+v"(q[2]),"+v"(q[3]),"+v"(q[4]),"+v"(q[5]),
                 "+v"(q[6]),"+v"(q[7]),"+v"(q[8]),"+v"(q[9]),"+v"(q[10]),"+v"(q[11]),
                 "+v"(q[12]),"+v"(q[13]),"+v"(q[14]),"+v"(q[15]) :: "memory");
  __builtin_amdgcn_sched_barrier(0);
}

__device__ __forceinline__ bool okq(const u32x4* q) {
  const unsigned S = 0xFFFFFFFFu;
  bool bad = false;
#pragma unroll
  for (int i = 0; i < 16; ++i)
    bad |= (q[i][0] == S) | (q[i][1] == S) | (q[i][2] == S) | (q[i][3] == S);
  return !bad;
}
__device__ __forceinline__ void pollx(const short* p0, const short* p1, u32x4* q) {
  ld16_coh(p0, p1, q);
  while (!__all(okq(q))) { __builtin_amdgcn_s_sleep(1); ld16_coh(p0, p1, q); }
}

// ---------------- embedding gather + mask ----------------
__global__ void k_embed(const int* __restrict__ x, const float* __restrict__ tab,
                        unsigned short* __restrict__ emb, int* __restrict__ mask) {
  int t = blockIdx.x, b = blockIdx.y;
  int tok = x[b * S_LEN + t];
  if (threadIdx.x == 0) mask[t * NB + b] = (tok != 0);
  const float4* src = (const float4*)(tab + (size_t)tok * UDIM);
  ushort4* dst = (ushort4*)(emb + ((size_t)t * NB + b) * UDIM);
  int i = threadIdx.x;
  float4 v = src[i];
  ushort4 o;
  o.x = f2bf(v.x); o.y = f2bf(v.y); o.z = f2bf(v.z); o.w = f2bf(v.w);
  dst[i] = o;
}

// ---------------- weight transpose/convert ----------------
__global__ void k_wprep(WPtrs wp, unsigned short* __restrict__ wsW) {
  int bid = blockIdx.x;
  int kt = bid & 31; bid >>= 5;
  int g  = bid % 3;  bid /= 3;
  int wg = bid & 31; bid >>= 5;
  int slab = bid;                        // 0..7 : (chain, mat)
  const float* src = wp.p[slab];
  int tid = threadIdx.x;
  int r = tid >> 4, cc = tid & 15;
  __shared__ float ldsT[16][17];
  ldsT[cc][r] = src[(size_t)(kt * 16 + r) * 1536 + g * 512 + wg * 16 + cc];
  __syncthreads();
  size_t off = ((size_t)slab * WGS + wg) * (48 * 512) + (size_t)(g * 16 + r) * 512 + kt * 16 + cc;
  wsW[off] = f2bf(ldsT[r][cc]);
}

// ---------------- persistent recurrent kernel ----------------
// 256 WGs; presumed XCD = bid&7. Chains 0..3 on XCDs 0..3 (32 WGs each);
// XCDs 4..7 idle-exit. Intra-chain h exchange: plain stores into a 16-slot
// ring (own-XCD L2) + sc0 sentinel-poll. Device-scope shadow (sc0 sc1, 257
// slots) keeps correctness if placement differs (latched fallback) and feeds
// the cross-XCD layer0->layer1 pipe. x-input is prefetched one step ahead.
__global__ __launch_bounds__(256, 1) void k_rnn(
    const unsigned short* __restrict__ wsW, const unsigned short* __restrict__ emb,
    unsigned short* __restrict__ hfast, unsigned short* __restrict__ shist,
    const int* __restrict__ mask, const float* __restrict__ state,
    BPtrs bp, float* __restrict__ out) {
  int bid = blockIdx.x;
  int xcd = bid & 7;
  if (xcd >= 4) return;                  // idle half of the GPU

  __shared__ short sW[2 * 48 * 512];        // 98304 B, XOR-swizzled rows
  __shared__ float sAcc[2][2][2][32][48];   // [parity][khalf][mat] 49152 B
  __shared__ float sBias[2][48];
  __shared__ unsigned char sMask[S_LEN][NB];

  int tid = threadIdx.x;
  int c = xcd;                            // chain == presumed XCD
  int w = bid >> 3;                       // wg-in-chain 0..31
  int layer = c & 1;
  bool back = (c >= 2);
  int lane = tid & 63;
  int wave = tid >> 6;
  int mat = wave & 1;                     // 0: x@k, 1: h@rk
  int kh = wave >> 1;                     // K-half

  int cb = tid >> 3;
  int cj = (tid & 7) << 1;
  float hreg0, hreg1, preg0 = 0.f, preg1 = 0.f;

  // ---- init: weights -> LDS (swizzled), biases, mask, state ----
  {
    const size_t slabSz = 48 * 512;
    for (int ch = tid; ch < 2 * 48 * 64; ch += 256) {
      int m = ch / (48 * 64);
      int rem = ch % (48 * 64);
      int nl = rem >> 6;
      int k16 = rem & 63;
      const unsigned short* sp =
          wsW + ((size_t)((c * 2 + m) * WGS) + w) * slabSz + (size_t)nl * 512 + k16 * 8;
      bf16x8 val = *(const bf16x8*)sp;
      int byte = m * 49152 + nl * 1024 + ((k16 * 16) ^ ((nl & 7) << 4));
      *(bf16x8*)((char*)sW + byte) = val;
    }
    const float* bptr = bp.p[c];
    for (int i = tid; i < 96; i += 256) {
      int m = i / 48, nl = i % 48;
      int col = (nl / 16) * 512 + w * 16 + (nl & 15);
      sBias[m][nl] = bptr[m * 1536 + col];
    }
    for (int i = tid; i < S_LEN * NB; i += 256)
      sMask[i >> 5][i & 31] = (unsigned char)(mask[i] != 0);
    int col = w * 16 + cj;
    hreg0 = state[((size_t)c * NB + cb) * UDIM + col];
    hreg1 = state[((size_t)c * NB + cb) * UDIM + col + 1];
    unsigned pk = (unsigned)f2bf(hreg0) | ((unsigned)f2bf(hreg1) << 16);
    *(unsigned*)(hfast + ((size_t)(c * RING + 0) * NB + cb) * UDIM + col) = pk;   // ring slot 0
    st_u32c((unsigned*)(shist + ((size_t)(c * 257 + 0) * NB + cb) * UDIM + col), pk);
  }
  __syncthreads();

  u32x4 q[16];                // mat0: persists across iterations (prefetch)
  bool latched = false;       // mat1: fast-ring starved -> use shadow forever
  int r15 = lane & 15, quad = lane >> 4;
  int abase = r15 * UDIM + kh * 256 + quad * 8;
  int matbase = mat * 49152;

  for (int t = 0; t < S_LEN; ++t) {
    int p = t & 1;
    int treal = back ? (S_LEN - 1 - t) : t;

    if (mat == 0) {
      // ---- x input: prefetched; validate/refill ----
      const short* xb;
      if (layer == 0) xb = (const short*)(emb + (size_t)treal * NB * UDIM);
      else xb = (const short*)(shist + ((size_t)(c - 1) * 257 + (t + 1)) * (size_t)NB * UDIM);
      const short* p0 = xb + abase;
      const short* p1 = xb + abase + 16 * UDIM;
      if (t == 0) {
        pollx(p0, p1, q);
      } else {
        waitq(q);
        if (!__all(okq(q))) pollx(p0, p1, q);
      }
    } else {
      // ---- h input: fast ring poll (own-XCD L2), shadow fallback ----
      const short* rb = (const short*)(hfast + ((size_t)(c * RING + (t & 15)) * NB) * UDIM);
      const short* p0 = rb + abase;
      const short* p1 = rb + abase + 16 * UDIM;
      if (!latched) {
        ld16_fast(p0, p1, q);
        int tries = 0;
        while (!__all(okq(q))) {
          if (++tries > 512) { latched = true; break; }
          ld16_fast(p0, p1, q);
        }
      }
      if (latched) {
        const short* sb = (const short*)(shist + ((size_t)(c * 257 + t) * NB) * UDIM);
        pollx(sb + abase, sb + abase + 16 * UDIM, q);
      }
    }

    // ---- GEMM: (32 x 48) += A(32 x 256-half) * W(256-half x 48) ----
    f32x4 acc[2][3];
#pragma unroll
    for (int a = 0; a < 2; a++)
#pragma unroll
      for (int g = 0; g < 3; g++) acc[a][g] = (f32x4){0.f, 0.f, 0.f, 0.f};
#pragma unroll
    for (int kc = 0; kc < 8; ++kc) {
      bf16x8 a0 = q2b(q[kc]);
      bf16x8 a1 = q2b(q[kc + 8]);
#pragma unroll
      for (int g = 0; g < 3; ++g) {
        int nl = g * 16 + r15;
        int koff = kh * 512 + kc * 64 + quad * 16;
        int byte = matbase + nl * 1024 + (koff ^ ((nl & 7) << 4));
        bf16x8 bw = *(const bf16x8*)((const char*)sW + byte);
        acc[0][g] = __builtin_amdgcn_mfma_f32_16x16x32_bf16(a0, bw, acc[0][g], 0, 0, 0);
        acc[1][g] = __builtin_amdgcn_mfma_f32_16x16x32_bf16(a1, bw, acc[1][g], 0, 0, 0);
      }
    }

    // ---- prefetch next x (mat0 only, after q consumed) ----
    if (mat == 0 && t < S_LEN - 1) {
      const short* nxb;
      if (layer == 0) {
        int tn = back ? (S_LEN - 2 - t) : (t + 1);
        nxb = (const short*)(emb + (size_t)tn * NB * UDIM);
      } else {
        nxb = (const short*)(shist + ((size_t)(c - 1) * 257 + (t + 2)) * (size_t)NB * UDIM);
      }
      ld16_issue(nxb + abase, nxb + abase + 16 * UDIM, q);
    }

#pragma unroll
    for (int mt = 0; mt < 2; ++mt)
#pragma unroll
      for (int g = 0; g < 3; ++g)
#pragma unroll
        for (int rr = 0; rr < 4; ++rr)
          sAcc[p][kh][mat][mt * 16 + quad * 4 + rr][g * 16 + r15] = acc[mt][g][rr];
    __syncthreads();   // the only barrier per step (sAcc parity double-buffered)

    // ---- combine + GRU nonlinearity: thread owns (cb, cj), (cb, cj+1) ----
    {
      int b = cb, j0 = cj;
      bool m = sMask[treal][b] != 0;
      float hn0, hn1;
#pragma unroll
      for (int u = 0; u < 2; ++u) {
        int j = j0 + u;
        float az = sAcc[p][0][0][b][j]      + sAcc[p][1][0][b][j]      + sBias[0][j];
        float ar = sAcc[p][0][0][b][16 + j] + sAcc[p][1][0][b][16 + j] + sBias[0][16 + j];
        float ah = sAcc[p][0][0][b][32 + j] + sAcc[p][1][0][b][32 + j] + sBias[0][32 + j];
        float iz = sAcc[p][0][1][b][j]      + sAcc[p][1][1][b][j]      + sBias[1][j];
        float ir = sAcc[p][0][1][b][16 + j] + sAcc[p][1][1][b][16 + j] + sBias[1][16 + j];
        float ih = sAcc[p][0][1][b][32 + j] + sAcc[p][1][1][b][32 + j] + sBias[1][32 + j];
        float z = 1.f / (1.f + __expf(-(az + iz)));
        float r = 1.f / (1.f + __expf(-(ar + ir)));
        float pre = ah + r * ih;
        pre = fminf(fmaxf(pre, -30.f), 30.f);
        float e2 = __expf(2.f * pre);
        float hh = (e2 - 1.f) / (e2 + 1.f);
        float hold = (u == 0) ? hreg0 : hreg1;
        float hv = z * hold + (1.f - z) * hh;
        hv = m ? hv : hold;
        if (u == 0) hn0 = hv; else hn1 = hv;
      }
      hreg0 = hn0; hreg1 = hn1;
      unsigned pk = (unsigned)f2bf(hn0) | ((unsigned)f2bf(hn1) << 16);
      int col = w * 16 + j0;
      // fast ring publish (plain -> own-XCD L2)
      *(unsigned*)(hfast + ((size_t)(c * RING + ((t + 1) & 15)) * NB + b) * UDIM + col) = pk;
      // sentinel-reset slot t-2 (all peers provably consumed it)
      if (t >= 2)
        *(unsigned*)(hfast + ((size_t)(c * RING + ((t - 2) & 15)) * NB + b) * UDIM + col) =
            0xFFFFFFFFu;
      // device-scope shadow publish (cross-XCD consumers + fallback)
      st_u32c((unsigned*)(shist + ((size_t)(c * 257 + (t + 1)) * NB + b) * UDIM + col), pk);
      if (layer == 1) {
        float o0 = m ? hn0 : preg0;
        float o1 = m ? hn1 : preg1;
        preg0 = o0; preg1 = o1;
        *(float2*)(out + ((size_t)b * S_LEN + treal) * 1024 + (back ? 512 : 0) + col) =
            make_float2(o0, o1);
      }
      if (t == S_LEN - 1) {
        *(float2*)(out + (size_t)NB * S_LEN * 1024 + ((size_t)c * NB + b) * UDIM + col) =
            make_float2(hn0, hn1);
      }
    }
  }
}

extern "C" void kernel_launch(void* const* d_in, const int* in_sizes, int n_in,
                              void* d_out, int out_size, void* d_ws, size_t ws_size,
                              hipStream_t stream) {
  const int* x = (const int*)d_in[0];
  const float* state = (const float*)d_in[1];
  const float* tab = (const float*)d_in[2];
  WPtrs wp;
  wp.p[0] = (const float*)d_in[3];   // fk0
  wp.p[1] = (const float*)d_in[4];   // frk0
  wp.p[2] = (const float*)d_in[6];   // fk1
  wp.p[3] = (const float*)d_in[7];   // frk1
  wp.p[4] = (const float*)d_in[9];   // bk0
  wp.p[5] = (const float*)d_in[10];  // brk0
  wp.p[6] = (const float*)d_in[12];  // bk1
  wp.p[7] = (const float*)d_in[13];  // brk1
  BPtrs bp;
  bp.p[0] = (const float*)d_in[5];   // fb0
  bp.p[1] = (const float*)d_in[8];   // fb1
  bp.p[2] = (const float*)d_in[11];  // bb0
  bp.p[3] = (const float*)d_in[14];  // bb1
  float* out = (float*)d_out;

  char* ws = (char*)d_ws;
  size_t off = 0;
  unsigned short* wsW = (unsigned short*)(ws + off); off += (size_t)8 * 32 * 48 * 512 * 2;
  unsigned short* embp = (unsigned short*)(ws + off); off += (size_t)S_LEN * NB * UDIM * 2;
  int* maskp = (int*)(ws + off); off += (size_t)S_LEN * NB * 4;
  unsigned short* hfast = (unsigned short*)(ws + off);
  size_t fastBytes = (size_t)4 * RING * NB * UDIM * 2;  off += fastBytes;   // 2 MB
  unsigned short* shist = (unsigned short*)(ws + off);
  size_t shBytes = (size_t)4 * 257 * NB * UDIM * 2;     off += shBytes;     // 33.7 MB

  // poison both h buffers: 0xFF bytes -> every u32 is the sentinel
  hipMemsetAsync(hfast, 0xFF, fastBytes + shBytes, stream);
  k_embed<<<dim3(S_LEN, NB), 128, 0, stream>>>(x, tab, embp, maskp);
  k_wprep<<<8 * 32 * 3 * 32, 256, 0, stream>>>(wp, wsW);
  k_rnn<<<256, 256, 0, stream>>>(wsW, embp, hfast, shist, maskp, state, bp, out);
}